// Round 1
// baseline (959.802 us; speedup 1.0000x reference)
//
#include <hip/hip_runtime.h>

constexpr int N_NODES = 50000;
constexpr int N_EDGES = 800000;
constexpr float BN_EPS = 1e-5f;

// ---------------- degree / normalization ----------------
__global__ void k_deg(const int* __restrict__ row, int* __restrict__ deg) {
  int i = blockIdx.x * blockDim.x + threadIdx.x;
  int stride = gridDim.x * blockDim.x;
  for (; i < N_EDGES; i += stride) atomicAdd(&deg[row[i]], 1);
}

__global__ void k_disqrt(const int* __restrict__ deg, float* __restrict__ dis) {
  int i = blockIdx.x * blockDim.x + threadIdx.x;
  if (i < N_NODES) dis[i] = rsqrtf((float)(deg[i] + 1));
}

// ---------------- CSR build: 3-phase scan + scatter ----------------
__global__ void k_scan_part(const int* __restrict__ deg, int* __restrict__ bsum) {
  __shared__ int s[256];
  int t = threadIdx.x, i = blockIdx.x * 256 + t;
  s[t] = (i < N_NODES) ? deg[i] : 0;
  __syncthreads();
  for (int off = 128; off > 0; off >>= 1) {
    if (t < off) s[t] += s[t + off];
    __syncthreads();
  }
  if (t == 0) bsum[blockIdx.x] = s[0];
}

__global__ void k_scan_top(const int* __restrict__ bsum, int* __restrict__ boff, int nb) {
  __shared__ int s[256];
  int t = threadIdx.x;
  int v = (t < nb) ? bsum[t] : 0;
  s[t] = v;
  __syncthreads();
  for (int off = 1; off < 256; off <<= 1) {
    int x = (t >= off) ? s[t - off] : 0;
    __syncthreads();
    s[t] += x;
    __syncthreads();
  }
  if (t < nb) boff[t] = s[t] - v;  // exclusive
}

__global__ void k_scan_final(const int* __restrict__ deg, const int* __restrict__ boff,
                             int* __restrict__ row_start) {
  __shared__ int s[256];
  int t = threadIdx.x, i = blockIdx.x * 256 + t;
  int v = (i < N_NODES) ? deg[i] : 0;
  s[t] = v;
  __syncthreads();
  for (int off = 1; off < 256; off <<= 1) {
    int x = (t >= off) ? s[t - off] : 0;
    __syncthreads();
    s[t] += x;
    __syncthreads();
  }
  if (i < N_NODES) row_start[i] = boff[blockIdx.x] + s[t] - v;
  if (i == 0) row_start[N_NODES] = N_EDGES;
}

__global__ void k_scatter(const int* __restrict__ row, const int* __restrict__ col,
                          const int* __restrict__ row_start, int* __restrict__ fill,
                          int* __restrict__ col_sorted) {
  int i = blockIdx.x * blockDim.x + threadIdx.x;
  int stride = gridDim.x * blockDim.x;
  for (; i < N_EDGES; i += stride) {
    int r = row[i];
    int pos = row_start[r] + atomicAdd(&fill[r], 1);
    col_sorted[pos] = col[i];
  }
}

// ---------------- GEMM: hs = f(A) @ W * d_isqrt ----------------
// f(A) = relu(A*scale + shift) when APPLY_BN, else A.
// A: [N,256] row-major, W: [256,D] row-major. BM=128, KT=32, 256 thr, 8x16 utile.
template <int D, bool APPLY_BN>
__global__ __launch_bounds__(256, 2) void k_gemm(const float* __restrict__ A,
                                                 const float* __restrict__ W,
                                                 const float* __restrict__ ss,  // scale[256],shift[256]
                                                 const float* __restrict__ dis,
                                                 float* __restrict__ hs) {
  constexpr int BM = 128, KT = 32, K = 256;
  constexpr int NG = D / 64;  // column groups of 4 per thread (stride 64)
  __shared__ float As[KT][BM];  // transposed: [k][row]
  __shared__ float Ws[KT][D];
  const int tid = threadIdx.x;
  const int tx = tid & 15, ty = tid >> 4;
  const int rb = blockIdx.x * BM;

  float acc[8][NG][4];
#pragma unroll
  for (int r = 0; r < 8; ++r)
#pragma unroll
    for (int g = 0; g < NG; ++g)
#pragma unroll
      for (int m = 0; m < 4; ++m) acc[r][g][m] = 0.f;

  for (int kt = 0; kt < K; kt += KT) {
// stage A (transpose into LDS), BN+relu applied on load
#pragma unroll
    for (int it = 0; it < 4; ++it) {
      int idx = tid + it * 256;          // 1024 float4 tasks
      int r = idx & 127, kq = idx >> 7;  // kq in [0,8)
      int grow = rb + r;
      int gr = grow < N_NODES ? grow : N_NODES - 1;
      float4 v = *reinterpret_cast<const float4*>(&A[(size_t)gr * K + kt + kq * 4]);
      float e[4] = {v.x, v.y, v.z, v.w};
      if (APPLY_BN) {
#pragma unroll
        for (int q = 0; q < 4; ++q) {
          int k = kt + kq * 4 + q;
          e[q] = fmaxf(e[q] * ss[k] + ss[256 + k], 0.f);
        }
      }
#pragma unroll
      for (int q = 0; q < 4; ++q) As[kq * 4 + q][r] = e[q];
    }
// stage W
#pragma unroll
    for (int it = 0; it < KT * D / 4 / 256; ++it) {
      int f = tid + it * 256;
      int k = f / (D / 4), cq = f % (D / 4);
      *reinterpret_cast<float4*>(&Ws[k][cq * 4]) =
          *reinterpret_cast<const float4*>(&W[(size_t)(kt + k) * D + cq * 4]);
    }
    __syncthreads();

#pragma unroll 4
    for (int k = 0; k < KT; ++k) {
      float a[8];
      *reinterpret_cast<float4*>(&a[0]) = *reinterpret_cast<float4*>(&As[k][ty * 8]);
      *reinterpret_cast<float4*>(&a[4]) = *reinterpret_cast<float4*>(&As[k][ty * 8 + 4]);
      float w[NG][4];
#pragma unroll
      for (int g = 0; g < NG; ++g)
        *reinterpret_cast<float4*>(&w[g][0]) =
            *reinterpret_cast<float4*>(&Ws[k][g * 64 + tx * 4]);
#pragma unroll
      for (int r = 0; r < 8; ++r)
#pragma unroll
        for (int g = 0; g < NG; ++g)
#pragma unroll
          for (int m = 0; m < 4; ++m) acc[r][g][m] = fmaf(a[r], w[g][m], acc[r][g][m]);
    }
    __syncthreads();
  }

// epilogue: scale by d_isqrt[row], store
#pragma unroll
  for (int r = 0; r < 8; ++r) {
    int grow = rb + ty * 8 + r;
    if (grow >= N_NODES) break;
    float di = dis[grow];
#pragma unroll
    for (int g = 0; g < NG; ++g) {
      float4 o;
      o.x = acc[r][g][0] * di;
      o.y = acc[r][g][1] * di;
      o.z = acc[r][g][2] * di;
      o.w = acc[r][g][3] * di;
      *reinterpret_cast<float4*>(&hs[(size_t)grow * D + g * 64 + tx * 4]) = o;
    }
  }
}

// ---------------- aggregation: pre[i] = dis[i]*(hs[i] + sum_nbr hs[c]) + b ----------------
template <int D>
__global__ void k_agg(const float* __restrict__ hs, const int* __restrict__ col_sorted,
                      const int* __restrict__ row_start, const float* __restrict__ dis,
                      const float* __restrict__ bias, float* __restrict__ pre) {
  int node = blockIdx.x;
  int t = threadIdx.x;
  float acc = hs[(size_t)node * D + t];
  int s = row_start[node], e = row_start[node + 1];
  for (int p = s; p < e; ++p) {
    int c = col_sorted[p];
    acc += hs[(size_t)c * D + t];
  }
  pre[(size_t)node * D + t] = acc * dis[node] + bias[t];
}

// layer-3 aggregation fused with log_softmax (D=128, 2 waves/block)
__global__ void k_agg_lsm(const float* __restrict__ hs, const int* __restrict__ col_sorted,
                          const int* __restrict__ row_start, const float* __restrict__ dis,
                          const float* __restrict__ bias, float* __restrict__ out) {
  constexpr int D = 128;
  int node = blockIdx.x, t = threadIdx.x;
  float acc = hs[(size_t)node * D + t];
  int s = row_start[node], e = row_start[node + 1];
  for (int p = s; p < e; ++p) acc += hs[(size_t)col_sorted[p] * D + t];
  float v = acc * dis[node] + bias[t];

  __shared__ float red[4];
  float m = v;
#pragma unroll
  for (int o = 1; o < 64; o <<= 1) m = fmaxf(m, __shfl_xor(m, o));
  if ((t & 63) == 0) red[t >> 6] = m;
  __syncthreads();
  m = fmaxf(red[0], red[1]);
  float ex = expf(v - m);
  float sum = ex;
#pragma unroll
  for (int o = 1; o < 64; o <<= 1) sum += __shfl_xor(sum, o);
  if ((t & 63) == 0) red[2 + (t >> 6)] = sum;
  __syncthreads();
  sum = red[2] + red[3];
  out[(size_t)node * D + t] = v - m - logf(sum);
}

// ---------------- batchnorm stats / merge ----------------
__global__ void k_bnstats(const float* __restrict__ pre, float* __restrict__ sum,
                          float* __restrict__ sq) {
  int t = threadIdx.x;  // 256 = one column per thread
  float a = 0.f, b = 0.f;
  for (int i = blockIdx.x; i < N_NODES; i += gridDim.x) {
    float v = pre[(size_t)i * 256 + t];
    a += v;
    b += v * v;
  }
  atomicAdd(&sum[t], a);
  atomicAdd(&sq[t], b);
}

__global__ void k_bnfinal(const float* __restrict__ sum, const float* __restrict__ sq,
                          const float* __restrict__ gamma, const float* __restrict__ beta,
                          float* __restrict__ ss) {
  int t = threadIdx.x;
  float mu = sum[t] * (1.f / N_NODES);
  float var = sq[t] * (1.f / N_NODES) - mu * mu;
  float sc = gamma[t] * rsqrtf(var + BN_EPS);
  ss[t] = sc;
  ss[256 + t] = beta[t] - mu * sc;
}

// ---------------- launcher ----------------
extern "C" void kernel_launch(void* const* d_in, const int* in_sizes, int n_in,
                              void* d_out, int out_size, void* d_ws, size_t ws_size,
                              hipStream_t stream) {
  const float* x = (const float*)d_in[0];
  const int* erow = (const int*)d_in[1];
  const int* ecol = erow + N_EDGES;
  const float* W0 = (const float*)d_in[2];
  const float* b0 = (const float*)d_in[3];
  const float* W1 = (const float*)d_in[4];
  const float* b1 = (const float*)d_in[5];
  const float* W2 = (const float*)d_in[6];
  const float* b2 = (const float*)d_in[7];
  const float* g0 = (const float*)d_in[8];
  const float* be0 = (const float*)d_in[9];
  const float* g1 = (const float*)d_in[10];
  const float* be1 = (const float*)d_in[11];
  float* out = (float*)d_out;

  char* ws = (char*)d_ws;
  size_t off = 0;
  auto take = [&](size_t bytes) {
    char* p = ws + off;
    off = (off + bytes + 255) & ~(size_t)255;
    return p;
  };
  int* deg = (int*)take(N_NODES * 4);
  int* fill = (int*)take(N_NODES * 4);
  float* cs0 = (float*)take(256 * 4);
  float* cq0 = (float*)take(256 * 4);
  float* cs1 = (float*)take(256 * 4);
  float* cq1 = (float*)take(256 * 4);
  size_t zero_bytes = off;  // everything above must start at 0 each call
  float* dis = (float*)take(N_NODES * 4);
  int* row_start = (int*)take((N_NODES + 1) * 4);
  int* bsum = (int*)take(256 * 4);
  int* boff = (int*)take(256 * 4);
  float* ss0 = (float*)take(512 * 4);
  float* ss1 = (float*)take(512 * 4);
  int* col_sorted = (int*)take((size_t)N_EDGES * 4);
  float* hs = (float*)take((size_t)N_NODES * 256 * 4);
  float* pre = (float*)take((size_t)N_NODES * 256 * 4);
  if (off > ws_size) return;  // workspace too small; fail loudly via wrong output

  hipMemsetAsync(d_ws, 0, zero_bytes, stream);

  k_deg<<<1024, 256, 0, stream>>>(erow, deg);
  k_disqrt<<<(N_NODES + 255) / 256, 256, 0, stream>>>(deg, dis);
  int nb = (N_NODES + 255) / 256;  // 196
  k_scan_part<<<nb, 256, 0, stream>>>(deg, bsum);
  k_scan_top<<<1, 256, 0, stream>>>(bsum, boff, nb);
  k_scan_final<<<nb, 256, 0, stream>>>(deg, boff, row_start);
  k_scatter<<<1024, 256, 0, stream>>>(erow, ecol, row_start, fill, col_sorted);

  int gemm_grid = (N_NODES + 127) / 128;
  // layer 0
  k_gemm<256, false><<<gemm_grid, 256, 0, stream>>>(x, W0, nullptr, dis, hs);
  k_agg<256><<<N_NODES, 256, 0, stream>>>(hs, col_sorted, row_start, dis, b0, pre);
  k_bnstats<<<128, 256, 0, stream>>>(pre, cs0, cq0);
  k_bnfinal<<<1, 256, 0, stream>>>(cs0, cq0, g0, be0, ss0);
  // layer 1
  k_gemm<256, true><<<gemm_grid, 256, 0, stream>>>(pre, W1, ss0, dis, hs);
  k_agg<256><<<N_NODES, 256, 0, stream>>>(hs, col_sorted, row_start, dis, b1, pre);
  k_bnstats<<<128, 256, 0, stream>>>(pre, cs1, cq1);
  k_bnfinal<<<1, 256, 0, stream>>>(cs1, cq1, g1, be1, ss1);
  // layer 2 + log_softmax
  k_gemm<128, true><<<gemm_grid, 256, 0, stream>>>(pre, W2, ss1, dis, hs);
  k_agg_lsm<<<N_NODES, 128, 0, stream>>>(hs, col_sorted, row_start, dis, b2, out);
}

// Round 2
// 638.773 us; speedup vs baseline: 1.5026x; 1.5026x over previous
//
#include <hip/hip_runtime.h>

constexpr int N_NODES = 50000;
constexpr int N_EDGES = 800000;
constexpr float BN_EPS = 1e-5f;

typedef __attribute__((ext_vector_type(8))) short short8;
typedef __attribute__((ext_vector_type(4))) float f32x4;

__device__ __forceinline__ float bf2f(ushort u) {
  union { uint i; float f; } v;
  v.i = ((uint)u) << 16;
  return v.f;
}
__device__ __forceinline__ ushort f2bf(float f) {
  union { float f; uint i; } v;
  v.f = f;
  uint r = v.i + 0x7fff + ((v.i >> 16) & 1);  // RNE
  return (ushort)(r >> 16);
}

// ---------------- degree / normalization ----------------
__global__ void k_deg(const int* __restrict__ row, int* __restrict__ deg) {
  int i = blockIdx.x * blockDim.x + threadIdx.x;
  int stride = gridDim.x * blockDim.x;
  for (; i < N_EDGES; i += stride) atomicAdd(&deg[row[i]], 1);
}

__global__ void k_disqrt(const int* __restrict__ deg, float* __restrict__ dis) {
  int i = blockIdx.x * blockDim.x + threadIdx.x;
  if (i < N_NODES) dis[i] = rsqrtf((float)(deg[i] + 1));
}

// ---------------- CSR build: 3-phase scan + scatter ----------------
__global__ void k_scan_part(const int* __restrict__ deg, int* __restrict__ bsum) {
  __shared__ int s[256];
  int t = threadIdx.x, i = blockIdx.x * 256 + t;
  s[t] = (i < N_NODES) ? deg[i] : 0;
  __syncthreads();
  for (int off = 128; off > 0; off >>= 1) {
    if (t < off) s[t] += s[t + off];
    __syncthreads();
  }
  if (t == 0) bsum[blockIdx.x] = s[0];
}

__global__ void k_scan_top(const int* __restrict__ bsum, int* __restrict__ boff, int nb) {
  __shared__ int s[256];
  int t = threadIdx.x;
  int v = (t < nb) ? bsum[t] : 0;
  s[t] = v;
  __syncthreads();
  for (int off = 1; off < 256; off <<= 1) {
    int x = (t >= off) ? s[t - off] : 0;
    __syncthreads();
    s[t] += x;
    __syncthreads();
  }
  if (t < nb) boff[t] = s[t] - v;  // exclusive
}

__global__ void k_scan_final(const int* __restrict__ deg, const int* __restrict__ boff,
                             int* __restrict__ row_start) {
  __shared__ int s[256];
  int t = threadIdx.x, i = blockIdx.x * 256 + t;
  int v = (i < N_NODES) ? deg[i] : 0;
  s[t] = v;
  __syncthreads();
  for (int off = 1; off < 256; off <<= 1) {
    int x = (t >= off) ? s[t - off] : 0;
    __syncthreads();
    s[t] += x;
    __syncthreads();
  }
  if (i < N_NODES) row_start[i] = boff[blockIdx.x] + s[t] - v;
  if (i == 0) row_start[N_NODES] = N_EDGES;
}

__global__ void k_scatter(const int* __restrict__ row, const int* __restrict__ col,
                          const int* __restrict__ row_start, int* __restrict__ fill,
                          int* __restrict__ col_sorted) {
  int i = blockIdx.x * blockDim.x + threadIdx.x;
  int stride = gridDim.x * blockDim.x;
  for (; i < N_EDGES; i += stride) {
    int r = row[i];
    int pos = row_start[r] + atomicAdd(&fill[r], 1);
    col_sorted[pos] = col[i];
  }
}

// ---------------- W transpose to bf16: Wt[n][k] = bf16(W[k][n]) ----------------
__global__ void k_wt(const float* __restrict__ W, ushort* __restrict__ Wt, int K, int N) {
  int idx = blockIdx.x * 256 + threadIdx.x;
  if (idx >= K * N) return;
  int n = idx / K, k = idx % K;
  Wt[idx] = f2bf(W[(size_t)k * N + n]);
}

// ---------------- bf16 MFMA GEMM: hs = bf16( f(A) @ W * d_isqrt ) ----------------
// f(A) = relu(A*scale + shift) when APPLY_BN (ss = scale[256],shift[256]); else A.
// A: [N_NODES,256] f32 row-major; Wt: [D,256] bf16 (W transposed); hs: [N_NODES,D] bf16.
// BM=BN=128, BK=32, 256 threads = 4 waves in 2x2 grid, 64x64 per wave,
// 4x4 frags of mfma_f32_16x16x32_bf16.
template <int D, bool APPLY_BN>
__global__ __launch_bounds__(256, 2) void k_gemm_bf16(const float* __restrict__ A,
                                                      const ushort* __restrict__ Wt,
                                                      const float* __restrict__ ss,
                                                      const float* __restrict__ dis,
                                                      ushort* __restrict__ hs) {
  constexpr int BM = 128, BN = 128, BK = 32, K = 256;
  constexpr int LDP = BK + 8;  // 40 bf16 (80B) stride: conflict-free b128 frags
  __shared__ ushort As[BM * LDP];
  __shared__ ushort Bs[BN * LDP];
  const int tid = threadIdx.x;
  const int lane = tid & 63;
  const int wid = tid >> 6;
  const int wr = wid >> 1, wc = wid & 1;  // 2x2 wave grid
  constexpr int NB = D / BN;
  const int rb = (blockIdx.x / NB) * BM;
  const int cb = (blockIdx.x % NB) * BN;

  f32x4 acc[4][4];
#pragma unroll
  for (int m = 0; m < 4; ++m)
#pragma unroll
    for (int n = 0; n < 4; ++n) acc[m][n] = (f32x4)(0.f);

  for (int kt = 0; kt < K; kt += BK) {
    // stage A: 128 rows x 32 k, fp32 -> (BN+relu) -> bf16. 512 tasks of 8.
#pragma unroll
    for (int it = 0; it < 2; ++it) {
      int idx = tid + it * 256;
      int row = idx >> 2, kq = idx & 3;
      int gr = rb + row;
      if (gr >= N_NODES) gr = N_NODES - 1;
      const float4* src = reinterpret_cast<const float4*>(&A[(size_t)gr * K + kt + kq * 8]);
      float4 v0 = src[0], v1 = src[1];
      float e[8] = {v0.x, v0.y, v0.z, v0.w, v1.x, v1.y, v1.z, v1.w};
      if constexpr (APPLY_BN) {
#pragma unroll
        for (int q = 0; q < 8; ++q) {
          int k = kt + kq * 8 + q;
          e[q] = fmaxf(e[q] * ss[k] + ss[256 + k], 0.f);
        }
      }
      short8 pk;
#pragma unroll
      for (int q = 0; q < 8; ++q) pk[q] = (short)f2bf(e[q]);
      *reinterpret_cast<short8*>(&As[row * LDP + kq * 8]) = pk;
    }
    // stage B from Wt (already bf16, k-contiguous)
#pragma unroll
    for (int it = 0; it < 2; ++it) {
      int idx = tid + it * 256;
      int n = idx >> 2, kq = idx & 3;
      short8 v = *reinterpret_cast<const short8*>(&Wt[(size_t)(cb + n) * K + kt + kq * 8]);
      *reinterpret_cast<short8*>(&Bs[n * LDP + kq * 8]) = v;
    }
    __syncthreads();

    const int rl = lane & 15;
    const int kb = (lane >> 4) * 8;
    short8 af[4], bfr[4];
#pragma unroll
    for (int f = 0; f < 4; ++f) {
      af[f] = *reinterpret_cast<short8*>(&As[(wr * 64 + f * 16 + rl) * LDP + kb]);
      bfr[f] = *reinterpret_cast<short8*>(&Bs[(wc * 64 + f * 16 + rl) * LDP + kb]);
    }
#pragma unroll
    for (int m = 0; m < 4; ++m)
#pragma unroll
      for (int n = 0; n < 4; ++n)
        acc[m][n] = __builtin_amdgcn_mfma_f32_16x16x32_bf16(af[m], bfr[n], acc[m][n], 0, 0, 0);
    __syncthreads();
  }

  // epilogue: *dis[row], cvt bf16, store. C frag: col=lane&15, row=(lane>>4)*4+j.
  const int cl = lane & 15, rq = lane >> 4;
#pragma unroll
  for (int m = 0; m < 4; ++m) {
    int rbase = rb + wr * 64 + m * 16 + rq * 4;
#pragma unroll
    for (int j = 0; j < 4; ++j) {
      int row = rbase + j;
      if (row >= N_NODES) continue;
      float di = dis[row];
#pragma unroll
      for (int n = 0; n < 4; ++n) {
        int col = cb + wc * 64 + n * 16 + cl;
        hs[(size_t)row * D + col] = f2bf(acc[m][n][j] * di);
      }
    }
  }
}

// ---------------- aggregation (bf16 gather): pre = dis*(self + sum_nbr) + b ----------------
// wave per node, lane holds 4 columns (D=256): 8B ushort4 gathers, fp32 accum.
__global__ __launch_bounds__(256) void k_agg_bf16(const ushort* __restrict__ hs,
                                                  const int* __restrict__ cs,
                                                  const int* __restrict__ rs,
                                                  const float* __restrict__ dis,
                                                  const float* __restrict__ bias,
                                                  float* __restrict__ pre) {
  int gw = (blockIdx.x * 256 + threadIdx.x) >> 6;
  if (gw >= N_NODES) return;
  int lane = threadIdx.x & 63;
  size_t coff = (size_t)lane * 4;
  ushort4 sv = *reinterpret_cast<const ushort4*>(&hs[(size_t)gw * 256 + coff]);
  float a0 = bf2f(sv.x), a1 = bf2f(sv.y), a2 = bf2f(sv.z), a3 = bf2f(sv.w);
  int s = rs[gw], e = rs[gw + 1];
  for (int p = s; p < e; ++p) {
    int c = cs[p];
    ushort4 v = *reinterpret_cast<const ushort4*>(&hs[(size_t)c * 256 + coff]);
    a0 += bf2f(v.x);
    a1 += bf2f(v.y);
    a2 += bf2f(v.z);
    a3 += bf2f(v.w);
  }
  float di = dis[gw];
  float4 b = *reinterpret_cast<const float4*>(&bias[lane * 4]);
  float4 o = {a0 * di + b.x, a1 * di + b.y, a2 * di + b.z, a3 * di + b.w};
  *reinterpret_cast<float4*>(&pre[(size_t)gw * 256 + coff]) = o;
}

// layer-3 aggregation fused with log_softmax, D=128, wave per node (lane: 2 cols)
__global__ __launch_bounds__(256) void k_agg_lsm_bf16(const ushort* __restrict__ hs,
                                                      const int* __restrict__ cs,
                                                      const int* __restrict__ rs,
                                                      const float* __restrict__ dis,
                                                      const float* __restrict__ bias,
                                                      float* __restrict__ out) {
  int gw = (blockIdx.x * 256 + threadIdx.x) >> 6;
  if (gw >= N_NODES) return;
  int lane = threadIdx.x & 63;
  ushort2 sv = *reinterpret_cast<const ushort2*>(&hs[(size_t)gw * 128 + lane * 2]);
  float a0 = bf2f(sv.x), a1 = bf2f(sv.y);
  int s = rs[gw], e = rs[gw + 1];
  for (int p = s; p < e; ++p) {
    int c = cs[p];
    ushort2 v = *reinterpret_cast<const ushort2*>(&hs[(size_t)c * 128 + lane * 2]);
    a0 += bf2f(v.x);
    a1 += bf2f(v.y);
  }
  float di = dis[gw];
  float2 b = *reinterpret_cast<const float2*>(&bias[lane * 2]);
  float v0 = a0 * di + b.x, v1 = a1 * di + b.y;
  float m = fmaxf(v0, v1);
#pragma unroll
  for (int o = 1; o < 64; o <<= 1) m = fmaxf(m, __shfl_xor(m, o));
  float sum = __expf(v0 - m) + __expf(v1 - m);
#pragma unroll
  for (int o = 1; o < 64; o <<= 1) sum += __shfl_xor(sum, o);
  float ls = m + logf(sum);
  float2 o2 = {v0 - ls, v1 - ls};
  *reinterpret_cast<float2*>(&out[(size_t)gw * 128 + lane * 2]) = o2;
}

// ---------------- batchnorm stats / merge ----------------
__global__ void k_bnstats(const float* __restrict__ pre, float* __restrict__ sum,
                          float* __restrict__ sq) {
  int t = threadIdx.x;  // one column per thread
  float a = 0.f, b = 0.f;
  for (int i = blockIdx.x; i < N_NODES; i += gridDim.x) {
    float v = pre[(size_t)i * 256 + t];
    a += v;
    b += v * v;
  }
  atomicAdd(&sum[t], a);
  atomicAdd(&sq[t], b);
}

__global__ void k_bnfinal(const float* __restrict__ sum, const float* __restrict__ sq,
                          const float* __restrict__ gamma, const float* __restrict__ beta,
                          float* __restrict__ ss) {
  int t = threadIdx.x;
  float mu = sum[t] * (1.f / N_NODES);
  float var = sq[t] * (1.f / N_NODES) - mu * mu;
  float sc = gamma[t] * rsqrtf(var + BN_EPS);
  ss[t] = sc;
  ss[256 + t] = beta[t] - mu * sc;
}

// ---------------- launcher ----------------
extern "C" void kernel_launch(void* const* d_in, const int* in_sizes, int n_in,
                              void* d_out, int out_size, void* d_ws, size_t ws_size,
                              hipStream_t stream) {
  const float* x = (const float*)d_in[0];
  const int* erow = (const int*)d_in[1];
  const int* ecol = erow + N_EDGES;
  const float* W0 = (const float*)d_in[2];
  const float* b0 = (const float*)d_in[3];
  const float* W1 = (const float*)d_in[4];
  const float* b1 = (const float*)d_in[5];
  const float* W2 = (const float*)d_in[6];
  const float* b2 = (const float*)d_in[7];
  const float* g0 = (const float*)d_in[8];
  const float* be0 = (const float*)d_in[9];
  const float* g1 = (const float*)d_in[10];
  const float* be1 = (const float*)d_in[11];
  float* out = (float*)d_out;

  char* ws = (char*)d_ws;
  size_t off = 0;
  auto take = [&](size_t bytes) {
    char* p = ws + off;
    off = (off + bytes + 255) & ~(size_t)255;
    return p;
  };
  int* deg = (int*)take(N_NODES * 4);
  int* fill = (int*)take(N_NODES * 4);
  float* cs0 = (float*)take(256 * 4);
  float* cq0 = (float*)take(256 * 4);
  float* cs1 = (float*)take(256 * 4);
  float* cq1 = (float*)take(256 * 4);
  size_t zero_bytes = off;  // must start at 0 each call
  float* dis = (float*)take(N_NODES * 4);
  int* row_start = (int*)take((N_NODES + 1) * 4);
  int* bsum = (int*)take(256 * 4);
  int* boff = (int*)take(256 * 4);
  float* ss0 = (float*)take(512 * 4);
  float* ss1 = (float*)take(512 * 4);
  ushort* Wt0 = (ushort*)take(256 * 256 * 2);
  ushort* Wt1 = (ushort*)take(256 * 256 * 2);
  ushort* Wt2 = (ushort*)take(256 * 128 * 2);
  int* col_sorted = (int*)take((size_t)N_EDGES * 4);
  ushort* hs = (ushort*)take((size_t)N_NODES * 256 * 2);
  float* pre = (float*)take((size_t)N_NODES * 256 * 4);
  if (off > ws_size) return;

  hipMemsetAsync(d_ws, 0, zero_bytes, stream);

  k_deg<<<1024, 256, 0, stream>>>(erow, deg);
  k_disqrt<<<(N_NODES + 255) / 256, 256, 0, stream>>>(deg, dis);
  int nb = (N_NODES + 255) / 256;  // 196
  k_scan_part<<<nb, 256, 0, stream>>>(deg, bsum);
  k_scan_top<<<1, 256, 0, stream>>>(bsum, boff, nb);
  k_scan_final<<<nb, 256, 0, stream>>>(deg, boff, row_start);
  k_scatter<<<1024, 256, 0, stream>>>(erow, ecol, row_start, fill, col_sorted);

  k_wt<<<(256 * 256 + 255) / 256, 256, 0, stream>>>(W0, Wt0, 256, 256);
  k_wt<<<(256 * 256 + 255) / 256, 256, 0, stream>>>(W1, Wt1, 256, 256);
  k_wt<<<(256 * 128 + 255) / 256, 256, 0, stream>>>(W2, Wt2, 256, 128);

  int mblocks = (N_NODES + 127) / 128;  // 391
  int agg_grid = (N_NODES * 64 + 255) / 256;  // 12500
  // layer 0
  k_gemm_bf16<256, false><<<mblocks * 2, 256, 0, stream>>>(x, Wt0, nullptr, dis, hs);
  k_agg_bf16<<<agg_grid, 256, 0, stream>>>(hs, col_sorted, row_start, dis, b0, pre);
  k_bnstats<<<128, 256, 0, stream>>>(pre, cs0, cq0);
  k_bnfinal<<<1, 256, 0, stream>>>(cs0, cq0, g0, be0, ss0);
  // layer 1
  k_gemm_bf16<256, true><<<mblocks * 2, 256, 0, stream>>>(pre, Wt1, ss0, dis, hs);
  k_agg_bf16<<<agg_grid, 256, 0, stream>>>(hs, col_sorted, row_start, dis, b1, pre);
  k_bnstats<<<128, 256, 0, stream>>>(pre, cs1, cq1);
  k_bnfinal<<<1, 256, 0, stream>>>(cs1, cq1, g1, be1, ss1);
  // layer 2 + log_softmax
  k_gemm_bf16<128, true><<<mblocks, 256, 0, stream>>>(pre, Wt2, ss1, dis, hs);
  k_agg_lsm_bf16<<<agg_grid, 256, 0, stream>>>(hs, col_sorted, row_start, dis, b2, out);
}

// Round 4
// 501.773 us; speedup vs baseline: 1.9128x; 1.2730x over previous
//
#include <hip/hip_runtime.h>

constexpr int N_NODES = 50000;
constexpr int N_EDGES = 800000;
constexpr float BN_EPS = 1e-5f;

typedef __attribute__((ext_vector_type(8))) short short8;
typedef __attribute__((ext_vector_type(4))) float f32x4;

__device__ __forceinline__ float bf2f(ushort u) {
  union { uint i; float f; } v;
  v.i = ((uint)u) << 16;
  return v.f;
}
__device__ __forceinline__ ushort f2bf(float f) {
  union { float f; uint i; } v;
  v.f = f;
  uint r = v.i + 0x7fff + ((v.i >> 16) & 1);  // RNE
  return (ushort)(r >> 16);
}

// ---------------- degree / normalization ----------------
__global__ void k_deg(const int* __restrict__ row, int* __restrict__ deg) {
  int i = blockIdx.x * blockDim.x + threadIdx.x;
  int stride = gridDim.x * blockDim.x;
  for (; i < N_EDGES; i += stride) atomicAdd(&deg[row[i]], 1);
}

__global__ void k_disqrt(const int* __restrict__ deg, float* __restrict__ dis) {
  int i = blockIdx.x * blockDim.x + threadIdx.x;
  if (i < N_NODES) dis[i] = rsqrtf((float)(deg[i] + 1));
}

// ---------------- CSR build: 3-phase scan + scatter ----------------
__global__ void k_scan_part(const int* __restrict__ deg, int* __restrict__ bsum) {
  __shared__ int s[256];
  int t = threadIdx.x, i = blockIdx.x * 256 + t;
  s[t] = (i < N_NODES) ? deg[i] : 0;
  __syncthreads();
  for (int off = 128; off > 0; off >>= 1) {
    if (t < off) s[t] += s[t + off];
    __syncthreads();
  }
  if (t == 0) bsum[blockIdx.x] = s[0];
}

__global__ void k_scan_top(const int* __restrict__ bsum, int* __restrict__ boff, int nb) {
  __shared__ int s[256];
  int t = threadIdx.x;
  int v = (t < nb) ? bsum[t] : 0;
  s[t] = v;
  __syncthreads();
  for (int off = 1; off < 256; off <<= 1) {
    int x = (t >= off) ? s[t - off] : 0;
    __syncthreads();
    s[t] += x;
    __syncthreads();
  }
  if (t < nb) boff[t] = s[t] - v;  // exclusive
}

__global__ void k_scan_final(const int* __restrict__ deg, const int* __restrict__ boff,
                             int* __restrict__ row_start) {
  __shared__ int s[256];
  int t = threadIdx.x, i = blockIdx.x * 256 + t;
  int v = (i < N_NODES) ? deg[i] : 0;
  s[t] = v;
  __syncthreads();
  for (int off = 1; off < 256; off <<= 1) {
    int x = (t >= off) ? s[t - off] : 0;
    __syncthreads();
    s[t] += x;
    __syncthreads();
  }
  if (i < N_NODES) row_start[i] = boff[blockIdx.x] + s[t] - v;
  if (i == 0) row_start[N_NODES] = N_EDGES;
}

__global__ void k_scatter(const int* __restrict__ row, const int* __restrict__ col,
                          const int* __restrict__ row_start, int* __restrict__ fill,
                          int* __restrict__ col_sorted) {
  int i = blockIdx.x * blockDim.x + threadIdx.x;
  int stride = gridDim.x * blockDim.x;
  for (; i < N_EDGES; i += stride) {
    int r = row[i];
    int pos = row_start[r] + atomicAdd(&fill[r], 1);
    col_sorted[pos] = col[i];
  }
}

// ---------------- W transpose to bf16: Wt[n][k] = bf16(W[k][n]) ----------------
__global__ void k_wt(const float* __restrict__ W, ushort* __restrict__ Wt, int K, int N) {
  int idx = blockIdx.x * 256 + threadIdx.x;
  if (idx >= K * N) return;
  int n = idx / K, k = idx % K;
  Wt[idx] = f2bf(W[(size_t)k * N + n]);
}

// ---------------- bf16 MFMA GEMM: hs = bf16( f(A) @ W * d_isqrt ) ----------------
// APPLY_BN: A is bf16 [N,256], f(A)=relu(A*scale+shift). else A fp32 [N,256], f=id.
// Wt: [D,256] bf16 (W transposed); hs: [N_NODES,D] bf16.
// BM=BN=128, BK=32, 256 threads = 4 waves (2x2), 64x64/wave, 4x4 mfma_16x16x32_bf16.
template <int D, bool APPLY_BN>
__global__ __launch_bounds__(256, 2) void k_gemm_bf16(const void* __restrict__ Av,
                                                      const ushort* __restrict__ Wt,
                                                      const float* __restrict__ ss,
                                                      const float* __restrict__ dis,
                                                      ushort* __restrict__ hs) {
  constexpr int BM = 128, BN = 128, BK = 32, K = 256;
  constexpr int LDP = BK + 8;  // 40 bf16 (80B) stride: conflict-free b128 frags
  __shared__ ushort As[BM * LDP];
  __shared__ ushort Bs[BN * LDP];
  const int tid = threadIdx.x;
  const int lane = tid & 63;
  const int wid = tid >> 6;
  const int wr = wid >> 1, wc = wid & 1;  // 2x2 wave grid
  constexpr int NB = D / BN;
  const int rb = (blockIdx.x / NB) * BM;
  const int cb = (blockIdx.x % NB) * BN;

  f32x4 acc[4][4];
#pragma unroll
  for (int m = 0; m < 4; ++m)
#pragma unroll
    for (int n = 0; n < 4; ++n) acc[m][n] = (f32x4)(0.f);

  for (int kt = 0; kt < K; kt += BK) {
    // stage A: 128 rows x 32 k. 512 tasks of 8 elems.
#pragma unroll
    for (int it = 0; it < 2; ++it) {
      int idx = tid + it * 256;
      int row = idx >> 2, kq = idx & 3;
      int gr = rb + row;
      if (gr >= N_NODES) gr = N_NODES - 1;
      float e[8];
      if constexpr (APPLY_BN) {
        const ushort* A = (const ushort*)Av;
        short8 v = *reinterpret_cast<const short8*>(&A[(size_t)gr * K + kt + kq * 8]);
#pragma unroll
        for (int q = 0; q < 8; ++q) {
          int k = kt + kq * 8 + q;
          e[q] = fmaxf(bf2f((ushort)v[q]) * ss[k] + ss[256 + k], 0.f);
        }
      } else {
        const float* A = (const float*)Av;
        const float4* src = reinterpret_cast<const float4*>(&A[(size_t)gr * K + kt + kq * 8]);
        float4 v0 = src[0], v1 = src[1];
        e[0] = v0.x; e[1] = v0.y; e[2] = v0.z; e[3] = v0.w;
        e[4] = v1.x; e[5] = v1.y; e[6] = v1.z; e[7] = v1.w;
      }
      short8 pk;
#pragma unroll
      for (int q = 0; q < 8; ++q) pk[q] = (short)f2bf(e[q]);
      *reinterpret_cast<short8*>(&As[row * LDP + kq * 8]) = pk;
    }
    // stage B from Wt (already bf16, k-contiguous)
#pragma unroll
    for (int it = 0; it < 2; ++it) {
      int idx = tid + it * 256;
      int n = idx >> 2, kq = idx & 3;
      short8 v = *reinterpret_cast<const short8*>(&Wt[(size_t)(cb + n) * K + kt + kq * 8]);
      *reinterpret_cast<short8*>(&Bs[n * LDP + kq * 8]) = v;
    }
    __syncthreads();

    const int rl = lane & 15;
    const int kb = (lane >> 4) * 8;
    short8 af[4], bfr[4];
#pragma unroll
    for (int f = 0; f < 4; ++f) {
      af[f] = *reinterpret_cast<short8*>(&As[(wr * 64 + f * 16 + rl) * LDP + kb]);
      bfr[f] = *reinterpret_cast<short8*>(&Bs[(wc * 64 + f * 16 + rl) * LDP + kb]);
    }
#pragma unroll
    for (int m = 0; m < 4; ++m)
#pragma unroll
      for (int n = 0; n < 4; ++n)
        acc[m][n] = __builtin_amdgcn_mfma_f32_16x16x32_bf16(af[m], bfr[n], acc[m][n], 0, 0, 0);
    __syncthreads();
  }

  // epilogue: *dis[row], cvt bf16, store. C frag: col=lane&15, row=(lane>>4)*4+j.
  const int cl = lane & 15;
  const int rq = lane >> 4;
#pragma unroll
  for (int m = 0; m < 4; ++m) {
    int rbase = rb + wr * 64 + m * 16 + rq * 4;
#pragma unroll
    for (int j = 0; j < 4; ++j) {
      int row = rbase + j;
      if (row >= N_NODES) continue;
      float di = dis[row];
#pragma unroll
      for (int n = 0; n < 4; ++n) {
        int col = cb + wc * 64 + n * 16 + cl;
        hs[(size_t)row * D + col] = f2bf(acc[m][n][j] * di);
      }
    }
  }
}

// ---------------- aggregation (bf16 gather): pre = bf16(dis*(self+sum_nbr)+b) -------
// wave per node, lane = 4 cols (D=256). Indices batch-loaded + __shfl broadcast;
// gather loop unrolled x2 to keep two 512B row-reads in flight.
__global__ __launch_bounds__(256) void k_agg_bf16(const ushort* __restrict__ hs,
                                                  const int* __restrict__ cs,
                                                  const int* __restrict__ rs,
                                                  const float* __restrict__ dis,
                                                  const float* __restrict__ bias,
                                                  ushort* __restrict__ pre) {
  int gw = (blockIdx.x * 256 + threadIdx.x) >> 6;
  if (gw >= N_NODES) return;
  int lane = threadIdx.x & 63;
  size_t coff = (size_t)lane * 4;
  ushort4 sv = *reinterpret_cast<const ushort4*>(&hs[(size_t)gw * 256 + coff]);
  float a0 = bf2f(sv.x), a1 = bf2f(sv.y), a2 = bf2f(sv.z), a3 = bf2f(sv.w);
  int s = rs[gw], e = rs[gw + 1];
  for (int base = s; base < e; base += 64) {
    int nav = min(64, e - base);
    int idx = (base + lane < e) ? cs[base + lane] : 0;
    int j = 0;
    for (; j + 1 < nav; j += 2) {
      int c0 = __shfl(idx, j), c1 = __shfl(idx, j + 1);
      ushort4 v0 = *reinterpret_cast<const ushort4*>(&hs[(size_t)c0 * 256 + coff]);
      ushort4 v1 = *reinterpret_cast<const ushort4*>(&hs[(size_t)c1 * 256 + coff]);
      a0 += bf2f(v0.x) + bf2f(v1.x);
      a1 += bf2f(v0.y) + bf2f(v1.y);
      a2 += bf2f(v0.z) + bf2f(v1.z);
      a3 += bf2f(v0.w) + bf2f(v1.w);
    }
    if (j < nav) {
      int c0 = __shfl(idx, j);
      ushort4 v0 = *reinterpret_cast<const ushort4*>(&hs[(size_t)c0 * 256 + coff]);
      a0 += bf2f(v0.x);
      a1 += bf2f(v0.y);
      a2 += bf2f(v0.z);
      a3 += bf2f(v0.w);
    }
  }
  float di = dis[gw];
  float4 b = *reinterpret_cast<const float4*>(&bias[lane * 4]);
  ushort4 o;
  o.x = f2bf(a0 * di + b.x);
  o.y = f2bf(a1 * di + b.y);
  o.z = f2bf(a2 * di + b.z);
  o.w = f2bf(a3 * di + b.w);
  *reinterpret_cast<ushort4*>(&pre[(size_t)gw * 256 + coff]) = o;
}

// layer-3 aggregation fused with log_softmax, D=128, wave per node (lane: 2 cols)
__global__ __launch_bounds__(256) void k_agg_lsm_bf16(const ushort* __restrict__ hs,
                                                      const int* __restrict__ cs,
                                                      const int* __restrict__ rs,
                                                      const float* __restrict__ dis,
                                                      const float* __restrict__ bias,
                                                      float* __restrict__ out) {
  int gw = (blockIdx.x * 256 + threadIdx.x) >> 6;
  if (gw >= N_NODES) return;
  int lane = threadIdx.x & 63;
  ushort2 sv = *reinterpret_cast<const ushort2*>(&hs[(size_t)gw * 128 + lane * 2]);
  float a0 = bf2f(sv.x), a1 = bf2f(sv.y);
  int s = rs[gw], e = rs[gw + 1];
  for (int base = s; base < e; base += 64) {
    int nav = min(64, e - base);
    int idx = (base + lane < e) ? cs[base + lane] : 0;
    int j = 0;
    for (; j + 1 < nav; j += 2) {
      int c0 = __shfl(idx, j), c1 = __shfl(idx, j + 1);
      ushort2 v0 = *reinterpret_cast<const ushort2*>(&hs[(size_t)c0 * 128 + lane * 2]);
      ushort2 v1 = *reinterpret_cast<const ushort2*>(&hs[(size_t)c1 * 128 + lane * 2]);
      a0 += bf2f(v0.x) + bf2f(v1.x);
      a1 += bf2f(v0.y) + bf2f(v1.y);
    }
    if (j < nav) {
      int c0 = __shfl(idx, j);
      ushort2 v0 = *reinterpret_cast<const ushort2*>(&hs[(size_t)c0 * 128 + lane * 2]);
      a0 += bf2f(v0.x);
      a1 += bf2f(v0.y);
    }
  }
  float di = dis[gw];
  float2 b = *reinterpret_cast<const float2*>(&bias[lane * 2]);
  float v0 = a0 * di + b.x, v1 = a1 * di + b.y;
  float m = fmaxf(v0, v1);
#pragma unroll
  for (int o = 1; o < 64; o <<= 1) m = fmaxf(m, __shfl_xor(m, o));
  float sum = __expf(v0 - m) + __expf(v1 - m);
#pragma unroll
  for (int o = 1; o < 64; o <<= 1) sum += __shfl_xor(sum, o);
  float ls = m + logf(sum);
  float2 o2 = {v0 - ls, v1 - ls};
  *reinterpret_cast<float2*>(&out[(size_t)gw * 128 + lane * 2]) = o2;
}

// ---------------- batchnorm stats (bf16 input, grid-stride, col-invariant) ---------
__global__ __launch_bounds__(256) void k_bnstats2(const ushort* __restrict__ pre,
                                                  float* __restrict__ sum,
                                                  float* __restrict__ sq) {
  int gtid = blockIdx.x * 256 + threadIdx.x;
  size_t stride = (size_t)gridDim.x * 256 * 2;  // elems; multiple of 256
  int c0 = (gtid * 2) & 255;
  float s0 = 0.f, s1 = 0.f, q0 = 0.f, q1 = 0.f;
  for (size_t i = (size_t)gtid * 2; i < (size_t)N_NODES * 256; i += stride) {
    ushort2 v = *reinterpret_cast<const ushort2*>(&pre[i]);
    float f0 = bf2f(v.x), f1 = bf2f(v.y);
    s0 += f0;
    q0 += f0 * f0;
    s1 += f1;
    q1 += f1 * f1;
  }
  atomicAdd(&sum[c0], s0);
  atomicAdd(&sq[c0], q0);
  atomicAdd(&sum[c0 + 1], s1);
  atomicAdd(&sq[c0 + 1], q1);
}

__global__ void k_bnfinal(const float* __restrict__ sum, const float* __restrict__ sq,
                          const float* __restrict__ gamma, const float* __restrict__ beta,
                          float* __restrict__ ss) {
  int t = threadIdx.x;
  float mu = sum[t] * (1.f / N_NODES);
  float var = sq[t] * (1.f / N_NODES) - mu * mu;
  float sc = gamma[t] * rsqrtf(var + BN_EPS);
  ss[t] = sc;
  ss[256 + t] = beta[t] - mu * sc;
}

// ---------------- launcher ----------------
extern "C" void kernel_launch(void* const* d_in, const int* in_sizes, int n_in,
                              void* d_out, int out_size, void* d_ws, size_t ws_size,
                              hipStream_t stream) {
  const float* x = (const float*)d_in[0];
  const int* erow = (const int*)d_in[1];
  const int* ecol = erow + N_EDGES;
  const float* W0 = (const float*)d_in[2];
  const float* b0 = (const float*)d_in[3];
  const float* W1 = (const float*)d_in[4];
  const float* b1 = (const float*)d_in[5];
  const float* W2 = (const float*)d_in[6];
  const float* b2 = (const float*)d_in[7];
  const float* g0 = (const float*)d_in[8];
  const float* be0 = (const float*)d_in[9];
  const float* g1 = (const float*)d_in[10];
  const float* be1 = (const float*)d_in[11];
  float* out = (float*)d_out;

  char* ws = (char*)d_ws;
  size_t off = 0;
  auto take = [&](size_t bytes) {
    char* p = ws + off;
    off = (off + bytes + 255) & ~(size_t)255;
    return p;
  };
  int* deg = (int*)take(N_NODES * 4);
  int* fill = (int*)take(N_NODES * 4);
  float* cs0 = (float*)take(256 * 4);
  float* cq0 = (float*)take(256 * 4);
  float* cs1 = (float*)take(256 * 4);
  float* cq1 = (float*)take(256 * 4);
  size_t zero_bytes = off;  // must start at 0 each call
  float* dis = (float*)take(N_NODES * 4);
  int* row_start = (int*)take((N_NODES + 1) * 4);
  int* bsum = (int*)take(256 * 4);
  int* boff = (int*)take(256 * 4);
  float* ss0 = (float*)take(512 * 4);
  float* ss1 = (float*)take(512 * 4);
  ushort* Wt0 = (ushort*)take(256 * 256 * 2);
  ushort* Wt1 = (ushort*)take(256 * 256 * 2);
  ushort* Wt2 = (ushort*)take(256 * 128 * 2);
  int* col_sorted = (int*)take((size_t)N_EDGES * 4);
  ushort* hs = (ushort*)take((size_t)N_NODES * 256 * 2);
  ushort* pre = (ushort*)take((size_t)N_NODES * 256 * 2);
  if (off > ws_size) return;

  hipMemsetAsync(d_ws, 0, zero_bytes, stream);

  k_deg<<<1024, 256, 0, stream>>>(erow, deg);
  k_disqrt<<<(N_NODES + 255) / 256, 256, 0, stream>>>(deg, dis);
  int nb = (N_NODES + 255) / 256;  // 196
  k_scan_part<<<nb, 256, 0, stream>>>(deg, bsum);
  k_scan_top<<<1, 256, 0, stream>>>(bsum, boff, nb);
  k_scan_final<<<nb, 256, 0, stream>>>(deg, boff, row_start);
  k_scatter<<<1024, 256, 0, stream>>>(erow, ecol, row_start, fill, col_sorted);

  k_wt<<<(256 * 256 + 255) / 256, 256, 0, stream>>>(W0, Wt0, 256, 256);
  k_wt<<<(256 * 256 + 255) / 256, 256, 0, stream>>>(W1, Wt1, 256, 256);
  k_wt<<<(256 * 128 + 255) / 256, 256, 0, stream>>>(W2, Wt2, 256, 128);

  int mblocks = (N_NODES + 127) / 128;  // 391
  int agg_grid = (N_NODES * 64 + 255) / 256;  // 12500
  // layer 0
  k_gemm_bf16<256, false><<<mblocks * 2, 256, 0, stream>>>(x, Wt0, nullptr, dis, hs);
  k_agg_bf16<<<agg_grid, 256, 0, stream>>>(hs, col_sorted, row_start, dis, b0, pre);
  k_bnstats2<<<768, 256, 0, stream>>>(pre, cs0, cq0);
  k_bnfinal<<<1, 256, 0, stream>>>(cs0, cq0, g0, be0, ss0);
  // layer 1
  k_gemm_bf16<256, true><<<mblocks * 2, 256, 0, stream>>>(pre, Wt1, ss0, dis, hs);
  k_agg_bf16<<<agg_grid, 256, 0, stream>>>(hs, col_sorted, row_start, dis, b1, pre);
  k_bnstats2<<<768, 256, 0, stream>>>(pre, cs1, cq1);
  k_bnfinal<<<1, 256, 0, stream>>>(cs1, cq1, g1, be1, ss1);
  // layer 2 + log_softmax
  k_gemm_bf16<128, true><<<mblocks, 256, 0, stream>>>(pre, Wt2, ss1, dis, hs);
  k_agg_lsm_bf16<<<agg_grid, 256, 0, stream>>>(hs, col_sorted, row_start, dis, b2, out);
}

// Round 5
// 411.070 us; speedup vs baseline: 2.3349x; 1.2207x over previous
//
#include <hip/hip_runtime.h>

constexpr int N_NODES = 50000;
constexpr int N_EDGES = 800000;
constexpr float BN_EPS = 1e-5f;
constexpr int BNA_BLOCKS = 512;

typedef __attribute__((ext_vector_type(8))) short short8;
typedef __attribute__((ext_vector_type(4))) float f32x4;

__device__ __forceinline__ float bf2f(ushort u) {
  union { uint i; float f; } v;
  v.i = ((uint)u) << 16;
  return v.f;
}
__device__ __forceinline__ ushort f2bf(float f) {
  union { float f; uint i; } v;
  v.f = f;
  uint r = v.i + 0x7fff + ((v.i >> 16) & 1);  // RNE
  return (ushort)(r >> 16);
}

// ---------------- degree / normalization ----------------
__global__ void k_deg(const int* __restrict__ row, int* __restrict__ deg) {
  int i = blockIdx.x * blockDim.x + threadIdx.x;
  int stride = gridDim.x * blockDim.x;
  for (; i < N_EDGES; i += stride) atomicAdd(&deg[row[i]], 1);
}

__global__ void k_disqrt(const int* __restrict__ deg, float* __restrict__ dis) {
  int i = blockIdx.x * blockDim.x + threadIdx.x;
  if (i < N_NODES) dis[i] = rsqrtf((float)(deg[i] + 1));
}

// ---------------- CSR build: 3-phase scan + scatter ----------------
__global__ void k_scan_part(const int* __restrict__ deg, int* __restrict__ bsum) {
  __shared__ int s[256];
  int t = threadIdx.x, i = blockIdx.x * 256 + t;
  s[t] = (i < N_NODES) ? deg[i] : 0;
  __syncthreads();
  for (int off = 128; off > 0; off >>= 1) {
    if (t < off) s[t] += s[t + off];
    __syncthreads();
  }
  if (t == 0) bsum[blockIdx.x] = s[0];
}

__global__ void k_scan_top(const int* __restrict__ bsum, int* __restrict__ boff, int nb) {
  __shared__ int s[256];
  int t = threadIdx.x;
  int v = (t < nb) ? bsum[t] : 0;
  s[t] = v;
  __syncthreads();
  for (int off = 1; off < 256; off <<= 1) {
    int x = (t >= off) ? s[t - off] : 0;
    __syncthreads();
    s[t] += x;
    __syncthreads();
  }
  if (t < nb) boff[t] = s[t] - v;  // exclusive
}

__global__ void k_scan_final(const int* __restrict__ deg, const int* __restrict__ boff,
                             int* __restrict__ row_start) {
  __shared__ int s[256];
  int t = threadIdx.x, i = blockIdx.x * 256 + t;
  int v = (i < N_NODES) ? deg[i] : 0;
  s[t] = v;
  __syncthreads();
  for (int off = 1; off < 256; off <<= 1) {
    int x = (t >= off) ? s[t - off] : 0;
    __syncthreads();
    s[t] += x;
    __syncthreads();
  }
  if (i < N_NODES) row_start[i] = boff[blockIdx.x] + s[t] - v;
  if (i == 0) row_start[N_NODES] = N_EDGES;
}

__global__ void k_scatter(const int* __restrict__ row, const int* __restrict__ col,
                          const int* __restrict__ row_start, int* __restrict__ fill,
                          int* __restrict__ col_sorted) {
  int i = blockIdx.x * blockDim.x + threadIdx.x;
  int stride = gridDim.x * blockDim.x;
  for (; i < N_EDGES; i += stride) {
    int r = row[i];
    int pos = row_start[r] + atomicAdd(&fill[r], 1);
    col_sorted[pos] = col[i];
  }
}

// ---------------- W transpose to bf16: Wt[n][k] = bf16(W[k][n]) ----------------
__global__ void k_wt(const float* __restrict__ W, ushort* __restrict__ Wt, int K, int N) {
  int idx = blockIdx.x * 256 + threadIdx.x;
  if (idx >= K * N) return;
  int n = idx / K, k = idx % K;
  Wt[idx] = f2bf(W[(size_t)k * N + n]);
}

// ---------------- bf16 MFMA GEMM: hs = bf16( f(A) @ W * d_isqrt ) ----------------
// APPLY_BN: A is bf16 [N,256], f(A)=relu(A*scale+shift). else A fp32 [N,256], f=id.
// Wt: [D,256] bf16 (W transposed); hs: [N_NODES,D] bf16.
// BM=BN=128, BK=32, 256 threads = 4 waves (2x2), 64x64/wave, 4x4 mfma_16x16x32_bf16.
template <int D, bool APPLY_BN>
__global__ __launch_bounds__(256, 2) void k_gemm_bf16(const void* __restrict__ Av,
                                                      const ushort* __restrict__ Wt,
                                                      const float* __restrict__ ss,
                                                      const float* __restrict__ dis,
                                                      ushort* __restrict__ hs) {
  constexpr int BM = 128, BN = 128, BK = 32, K = 256;
  constexpr int LDP = BK + 8;  // 40 bf16 (80B) stride: conflict-free b128 frags
  __shared__ ushort As[BM * LDP];
  __shared__ ushort Bs[BN * LDP];
  const int tid = threadIdx.x;
  const int lane = tid & 63;
  const int wid = tid >> 6;
  const int wr = wid >> 1, wc = wid & 1;  // 2x2 wave grid
  constexpr int NB = D / BN;
  const int rb = (blockIdx.x / NB) * BM;
  const int cb = (blockIdx.x % NB) * BN;

  f32x4 acc[4][4];
#pragma unroll
  for (int m = 0; m < 4; ++m)
#pragma unroll
    for (int n = 0; n < 4; ++n) acc[m][n] = (f32x4)(0.f);

  for (int kt = 0; kt < K; kt += BK) {
    // stage A: 128 rows x 32 k. 512 tasks of 8 elems.
#pragma unroll
    for (int it = 0; it < 2; ++it) {
      int idx = tid + it * 256;
      int row = idx >> 2, kq = idx & 3;
      int gr = rb + row;
      if (gr >= N_NODES) gr = N_NODES - 1;
      float e[8];
      if constexpr (APPLY_BN) {
        const ushort* A = (const ushort*)Av;
        short8 v = *reinterpret_cast<const short8*>(&A[(size_t)gr * K + kt + kq * 8]);
#pragma unroll
        for (int q = 0; q < 8; ++q) {
          int k = kt + kq * 8 + q;
          e[q] = fmaxf(bf2f((ushort)v[q]) * ss[k] + ss[256 + k], 0.f);
        }
      } else {
        const float* A = (const float*)Av;
        const float4* src = reinterpret_cast<const float4*>(&A[(size_t)gr * K + kt + kq * 8]);
        float4 v0 = src[0], v1 = src[1];
        e[0] = v0.x; e[1] = v0.y; e[2] = v0.z; e[3] = v0.w;
        e[4] = v1.x; e[5] = v1.y; e[6] = v1.z; e[7] = v1.w;
      }
      short8 pk;
#pragma unroll
      for (int q = 0; q < 8; ++q) pk[q] = (short)f2bf(e[q]);
      *reinterpret_cast<short8*>(&As[row * LDP + kq * 8]) = pk;
    }
    // stage B from Wt (already bf16, k-contiguous)
#pragma unroll
    for (int it = 0; it < 2; ++it) {
      int idx = tid + it * 256;
      int n = idx >> 2, kq = idx & 3;
      short8 v = *reinterpret_cast<const short8*>(&Wt[(size_t)(cb + n) * K + kt + kq * 8]);
      *reinterpret_cast<short8*>(&Bs[n * LDP + kq * 8]) = v;
    }
    __syncthreads();

    const int rl = lane & 15;
    const int kb = (lane >> 4) * 8;
    short8 af[4], bfr[4];
#pragma unroll
    for (int f = 0; f < 4; ++f) {
      af[f] = *reinterpret_cast<short8*>(&As[(wr * 64 + f * 16 + rl) * LDP + kb]);
      bfr[f] = *reinterpret_cast<short8*>(&Bs[(wc * 64 + f * 16 + rl) * LDP + kb]);
    }
#pragma unroll
    for (int m = 0; m < 4; ++m)
#pragma unroll
      for (int n = 0; n < 4; ++n)
        acc[m][n] = __builtin_amdgcn_mfma_f32_16x16x32_bf16(af[m], bfr[n], acc[m][n], 0, 0, 0);
    __syncthreads();
  }

  // epilogue: *dis[row], cvt bf16, store. C frag: col=lane&15, row=(lane>>4)*4+j.
  const int cl = lane & 15;
  const int rq = lane >> 4;
#pragma unroll
  for (int m = 0; m < 4; ++m) {
    int rbase = rb + wr * 64 + m * 16 + rq * 4;
#pragma unroll
    for (int j = 0; j < 4; ++j) {
      int row = rbase + j;
      if (row >= N_NODES) continue;
      float di = dis[row];
#pragma unroll
      for (int n = 0; n < 4; ++n) {
        int col = cb + wc * 64 + n * 16 + cl;
        hs[(size_t)row * D + col] = f2bf(acc[m][n][j] * di);
      }
    }
  }
}

// ---------------- aggregation (bf16 gather): pre = bf16(dis*(self+sum_nbr)+b) -------
// wave per node, lane = 4 cols (D=256). Indices batch-loaded + __shfl broadcast;
// gather loop unrolled x4 to keep four 512B row-reads in flight.
__global__ __launch_bounds__(256) void k_agg_bf16(const ushort* __restrict__ hs,
                                                  const int* __restrict__ cs,
                                                  const int* __restrict__ rs,
                                                  const float* __restrict__ dis,
                                                  const float* __restrict__ bias,
                                                  ushort* __restrict__ pre) {
  int gw = (blockIdx.x * 256 + threadIdx.x) >> 6;
  if (gw >= N_NODES) return;
  int lane = threadIdx.x & 63;
  size_t coff = (size_t)lane * 4;
  ushort4 sv = *reinterpret_cast<const ushort4*>(&hs[(size_t)gw * 256 + coff]);
  float a0 = bf2f(sv.x), a1 = bf2f(sv.y), a2 = bf2f(sv.z), a3 = bf2f(sv.w);
  int s = rs[gw], e = rs[gw + 1];
  for (int base = s; base < e; base += 64) {
    int nav = min(64, e - base);
    int idx = (base + lane < e) ? cs[base + lane] : 0;
    int j = 0;
    for (; j + 3 < nav; j += 4) {
      int c0 = __shfl(idx, j), c1 = __shfl(idx, j + 1);
      int c2 = __shfl(idx, j + 2), c3 = __shfl(idx, j + 3);
      ushort4 v0 = *reinterpret_cast<const ushort4*>(&hs[(size_t)c0 * 256 + coff]);
      ushort4 v1 = *reinterpret_cast<const ushort4*>(&hs[(size_t)c1 * 256 + coff]);
      ushort4 v2 = *reinterpret_cast<const ushort4*>(&hs[(size_t)c2 * 256 + coff]);
      ushort4 v3 = *reinterpret_cast<const ushort4*>(&hs[(size_t)c3 * 256 + coff]);
      a0 += bf2f(v0.x) + bf2f(v1.x) + bf2f(v2.x) + bf2f(v3.x);
      a1 += bf2f(v0.y) + bf2f(v1.y) + bf2f(v2.y) + bf2f(v3.y);
      a2 += bf2f(v0.z) + bf2f(v1.z) + bf2f(v2.z) + bf2f(v3.z);
      a3 += bf2f(v0.w) + bf2f(v1.w) + bf2f(v2.w) + bf2f(v3.w);
    }
    for (; j < nav; ++j) {
      int c0 = __shfl(idx, j);
      ushort4 v0 = *reinterpret_cast<const ushort4*>(&hs[(size_t)c0 * 256 + coff]);
      a0 += bf2f(v0.x);
      a1 += bf2f(v0.y);
      a2 += bf2f(v0.z);
      a3 += bf2f(v0.w);
    }
  }
  float di = dis[gw];
  float4 b = *reinterpret_cast<const float4*>(&bias[lane * 4]);
  ushort4 o;
  o.x = f2bf(a0 * di + b.x);
  o.y = f2bf(a1 * di + b.y);
  o.z = f2bf(a2 * di + b.z);
  o.w = f2bf(a3 * di + b.w);
  *reinterpret_cast<ushort4*>(&pre[(size_t)gw * 256 + coff]) = o;
}

// layer-3 aggregation fused with log_softmax, D=128, wave per node (lane: 2 cols)
__global__ __launch_bounds__(256) void k_agg_lsm_bf16(const ushort* __restrict__ hs,
                                                      const int* __restrict__ cs,
                                                      const int* __restrict__ rs,
                                                      const float* __restrict__ dis,
                                                      const float* __restrict__ bias,
                                                      float* __restrict__ out) {
  int gw = (blockIdx.x * 256 + threadIdx.x) >> 6;
  if (gw >= N_NODES) return;
  int lane = threadIdx.x & 63;
  ushort2 sv = *reinterpret_cast<const ushort2*>(&hs[(size_t)gw * 128 + lane * 2]);
  float a0 = bf2f(sv.x), a1 = bf2f(sv.y);
  int s = rs[gw], e = rs[gw + 1];
  for (int base = s; base < e; base += 64) {
    int nav = min(64, e - base);
    int idx = (base + lane < e) ? cs[base + lane] : 0;
    int j = 0;
    for (; j + 3 < nav; j += 4) {
      int c0 = __shfl(idx, j), c1 = __shfl(idx, j + 1);
      int c2 = __shfl(idx, j + 2), c3 = __shfl(idx, j + 3);
      ushort2 v0 = *reinterpret_cast<const ushort2*>(&hs[(size_t)c0 * 128 + lane * 2]);
      ushort2 v1 = *reinterpret_cast<const ushort2*>(&hs[(size_t)c1 * 128 + lane * 2]);
      ushort2 v2 = *reinterpret_cast<const ushort2*>(&hs[(size_t)c2 * 128 + lane * 2]);
      ushort2 v3 = *reinterpret_cast<const ushort2*>(&hs[(size_t)c3 * 128 + lane * 2]);
      a0 += bf2f(v0.x) + bf2f(v1.x) + bf2f(v2.x) + bf2f(v3.x);
      a1 += bf2f(v0.y) + bf2f(v1.y) + bf2f(v2.y) + bf2f(v3.y);
    }
    for (; j < nav; ++j) {
      int c0 = __shfl(idx, j);
      ushort2 v0 = *reinterpret_cast<const ushort2*>(&hs[(size_t)c0 * 128 + lane * 2]);
      a0 += bf2f(v0.x);
      a1 += bf2f(v0.y);
    }
  }
  float di = dis[gw];
  float2 b = *reinterpret_cast<const float2*>(&bias[lane * 2]);
  float v0 = a0 * di + b.x, v1 = a1 * di + b.y;
  float m = fmaxf(v0, v1);
#pragma unroll
  for (int o = 1; o < 64; o <<= 1) m = fmaxf(m, __shfl_xor(m, o));
  float sum = __expf(v0 - m) + __expf(v1 - m);
#pragma unroll
  for (int o = 1; o < 64; o <<= 1) sum += __shfl_xor(sum, o);
  float ls = m + logf(sum);
  float2 o2 = {v0 - ls, v1 - ls};
  *reinterpret_cast<float2*>(&out[(size_t)gw * 128 + lane * 2]) = o2;
}

// ---------------- batchnorm stats: two-phase, atomic-free ----------------
// Phase A: block handles 2 rows/iter (coalesced 1KB), regs accumulate per-col,
// LDS combine, write partial[block][512] (sum[256] | sq[256]).
__global__ __launch_bounds__(256) void k_bnstatsA(const ushort* __restrict__ pre,
                                                  float* __restrict__ partial) {
  int t = threadIdx.x;
  int rsub = t >> 7;         // 0/1: which row of the pair
  int cp = (t & 127) * 2;    // column pair
  float s0 = 0.f, s1 = 0.f, q0 = 0.f, q1 = 0.f;
  for (int r = blockIdx.x * 2 + rsub; r < N_NODES; r += BNA_BLOCKS * 2) {
    ushort2 v = *reinterpret_cast<const ushort2*>(&pre[(size_t)r * 256 + cp]);
    float f0 = bf2f(v.x), f1 = bf2f(v.y);
    s0 += f0;
    q0 += f0 * f0;
    s1 += f1;
    q1 += f1 * f1;
  }
  __shared__ float lsum[256], lsq[256];
  if (rsub) {
    lsum[cp] = s0;
    lsum[cp + 1] = s1;
    lsq[cp] = q0;
    lsq[cp + 1] = q1;
  }
  __syncthreads();
  if (!rsub) {
    float* p = &partial[(size_t)blockIdx.x * 512];
    p[cp] = s0 + lsum[cp];
    p[cp + 1] = s1 + lsum[cp + 1];
    p[256 + cp] = q0 + lsq[cp];
    p[256 + cp + 1] = q1 + lsq[cp + 1];
  }
}

// Phase B: 512 threads; thread t reduces partial[:,t] -> sum/sq.
__global__ __launch_bounds__(512) void k_bnstatsB(const float* __restrict__ partial,
                                                  float* __restrict__ sum,
                                                  float* __restrict__ sq) {
  int t = threadIdx.x;
  float a = 0.f;
#pragma unroll 8
  for (int b = 0; b < BNA_BLOCKS; ++b) a += partial[(size_t)b * 512 + t];
  if (t < 256) sum[t] = a;
  else sq[t - 256] = a;
}

__global__ void k_bnfinal(const float* __restrict__ sum, const float* __restrict__ sq,
                          const float* __restrict__ gamma, const float* __restrict__ beta,
                          float* __restrict__ ss) {
  int t = threadIdx.x;
  float mu = sum[t] * (1.f / N_NODES);
  float var = sq[t] * (1.f / N_NODES) - mu * mu;
  float sc = gamma[t] * rsqrtf(var + BN_EPS);
  ss[t] = sc;
  ss[256 + t] = beta[t] - mu * sc;
}

// ---------------- launcher ----------------
extern "C" void kernel_launch(void* const* d_in, const int* in_sizes, int n_in,
                              void* d_out, int out_size, void* d_ws, size_t ws_size,
                              hipStream_t stream) {
  const float* x = (const float*)d_in[0];
  const int* erow = (const int*)d_in[1];
  const int* ecol = erow + N_EDGES;
  const float* W0 = (const float*)d_in[2];
  const float* b0 = (const float*)d_in[3];
  const float* W1 = (const float*)d_in[4];
  const float* b1 = (const float*)d_in[5];
  const float* W2 = (const float*)d_in[6];
  const float* b2 = (const float*)d_in[7];
  const float* g0 = (const float*)d_in[8];
  const float* be0 = (const float*)d_in[9];
  const float* g1 = (const float*)d_in[10];
  const float* be1 = (const float*)d_in[11];
  float* out = (float*)d_out;

  char* ws = (char*)d_ws;
  size_t off = 0;
  auto take = [&](size_t bytes) {
    char* p = ws + off;
    off = (off + bytes + 255) & ~(size_t)255;
    return p;
  };
  int* deg = (int*)take(N_NODES * 4);
  int* fill = (int*)take(N_NODES * 4);
  size_t zero_bytes = off;  // deg+fill must start at 0 each call
  float* cs0 = (float*)take(256 * 4);
  float* cq0 = (float*)take(256 * 4);
  float* cs1 = (float*)take(256 * 4);
  float* cq1 = (float*)take(256 * 4);
  float* bnpart = (float*)take((size_t)BNA_BLOCKS * 512 * 4);
  float* dis = (float*)take(N_NODES * 4);
  int* row_start = (int*)take((N_NODES + 1) * 4);
  int* bsum = (int*)take(256 * 4);
  int* boff = (int*)take(256 * 4);
  float* ss0 = (float*)take(512 * 4);
  float* ss1 = (float*)take(512 * 4);
  ushort* Wt0 = (ushort*)take(256 * 256 * 2);
  ushort* Wt1 = (ushort*)take(256 * 256 * 2);
  ushort* Wt2 = (ushort*)take(256 * 128 * 2);
  int* col_sorted = (int*)take((size_t)N_EDGES * 4);
  ushort* hs = (ushort*)take((size_t)N_NODES * 256 * 2);
  ushort* pre = (ushort*)take((size_t)N_NODES * 256 * 2);
  if (off > ws_size) return;

  hipMemsetAsync(d_ws, 0, zero_bytes, stream);

  k_deg<<<1024, 256, 0, stream>>>(erow, deg);
  k_disqrt<<<(N_NODES + 255) / 256, 256, 0, stream>>>(deg, dis);
  int nb = (N_NODES + 255) / 256;  // 196
  k_scan_part<<<nb, 256, 0, stream>>>(deg, bsum);
  k_scan_top<<<1, 256, 0, stream>>>(bsum, boff, nb);
  k_scan_final<<<nb, 256, 0, stream>>>(deg, boff, row_start);
  k_scatter<<<1024, 256, 0, stream>>>(erow, ecol, row_start, fill, col_sorted);

  k_wt<<<(256 * 256 + 255) / 256, 256, 0, stream>>>(W0, Wt0, 256, 256);
  k_wt<<<(256 * 256 + 255) / 256, 256, 0, stream>>>(W1, Wt1, 256, 256);
  k_wt<<<(256 * 128 + 255) / 256, 256, 0, stream>>>(W2, Wt2, 256, 128);

  int mblocks = (N_NODES + 127) / 128;  // 391
  int agg_grid = (N_NODES * 64 + 255) / 256;  // 12500
  // layer 0
  k_gemm_bf16<256, false><<<mblocks * 2, 256, 0, stream>>>(x, Wt0, nullptr, dis, hs);
  k_agg_bf16<<<agg_grid, 256, 0, stream>>>(hs, col_sorted, row_start, dis, b0, pre);
  k_bnstatsA<<<BNA_BLOCKS, 256, 0, stream>>>(pre, bnpart);
  k_bnstatsB<<<1, 512, 0, stream>>>(bnpart, cs0, cq0);
  k_bnfinal<<<1, 256, 0, stream>>>(cs0, cq0, g0, be0, ss0);
  // layer 1
  k_gemm_bf16<256, true><<<mblocks * 2, 256, 0, stream>>>(pre, Wt1, ss0, dis, hs);
  k_agg_bf16<<<agg_grid, 256, 0, stream>>>(hs, col_sorted, row_start, dis, b1, pre);
  k_bnstatsA<<<BNA_BLOCKS, 256, 0, stream>>>(pre, bnpart);
  k_bnstatsB<<<1, 512, 0, stream>>>(bnpart, cs1, cq1);
  k_bnfinal<<<1, 256, 0, stream>>>(cs1, cq1, g1, be1, ss1);
  // layer 2 + log_softmax
  k_gemm_bf16<128, true><<<mblocks, 256, 0, stream>>>(pre, Wt2, ss1, dis, hs);
  k_agg_lsm_bf16<<<agg_grid, 256, 0, stream>>>(hs, col_sorted, row_start, dis, b2, out);
}

// Round 6
// 385.511 us; speedup vs baseline: 2.4897x; 1.0663x over previous
//
#include <hip/hip_runtime.h>

constexpr int N_NODES = 50000;
constexpr int N_EDGES = 800000;
constexpr float BN_EPS = 1e-5f;
constexpr int BNA_BLOCKS = 256;

typedef __attribute__((ext_vector_type(8))) short short8;
typedef __attribute__((ext_vector_type(4))) float f32x4;

__device__ __forceinline__ float bf2f(ushort u) {
  union { uint i; float f; } v;
  v.i = ((uint)u) << 16;
  return v.f;
}
__device__ __forceinline__ ushort f2bf(float f) {
  union { float f; uint i; } v;
  v.f = f;
  uint r = v.i + 0x7fff + ((v.i >> 16) & 1);  // RNE
  return (ushort)(r >> 16);
}

// ---------------- degree / normalization ----------------
__global__ void k_deg(const int* __restrict__ row, int* __restrict__ deg) {
  int i = blockIdx.x * blockDim.x + threadIdx.x;
  int stride = gridDim.x * blockDim.x;
  for (; i < N_EDGES; i += stride) atomicAdd(&deg[row[i]], 1);
}

__global__ void k_disqrt(const int* __restrict__ deg, float* __restrict__ dis) {
  int i = blockIdx.x * blockDim.x + threadIdx.x;
  if (i < N_NODES) dis[i] = rsqrtf((float)(deg[i] + 1));
}

// ---------------- CSR build: 3-phase scan + scatter ----------------
__global__ void k_scan_part(const int* __restrict__ deg, int* __restrict__ bsum) {
  __shared__ int s[256];
  int t = threadIdx.x, i = blockIdx.x * 256 + t;
  s[t] = (i < N_NODES) ? deg[i] : 0;
  __syncthreads();
  for (int off = 128; off > 0; off >>= 1) {
    if (t < off) s[t] += s[t + off];
    __syncthreads();
  }
  if (t == 0) bsum[blockIdx.x] = s[0];
}

__global__ void k_scan_top(const int* __restrict__ bsum, int* __restrict__ boff, int nb) {
  __shared__ int s[256];
  int t = threadIdx.x;
  int v = (t < nb) ? bsum[t] : 0;
  s[t] = v;
  __syncthreads();
  for (int off = 1; off < 256; off <<= 1) {
    int x = (t >= off) ? s[t - off] : 0;
    __syncthreads();
    s[t] += x;
    __syncthreads();
  }
  if (t < nb) boff[t] = s[t] - v;  // exclusive
}

__global__ void k_scan_final(const int* __restrict__ deg, const int* __restrict__ boff,
                             int* __restrict__ row_start) {
  __shared__ int s[256];
  int t = threadIdx.x, i = blockIdx.x * 256 + t;
  int v = (i < N_NODES) ? deg[i] : 0;
  s[t] = v;
  __syncthreads();
  for (int off = 1; off < 256; off <<= 1) {
    int x = (t >= off) ? s[t - off] : 0;
    __syncthreads();
    s[t] += x;
    __syncthreads();
  }
  if (i < N_NODES) row_start[i] = boff[blockIdx.x] + s[t] - v;
  if (i == 0) row_start[N_NODES] = N_EDGES;
}

__global__ void k_scatter(const int* __restrict__ row, const int* __restrict__ col,
                          const int* __restrict__ row_start, int* __restrict__ fill,
                          int* __restrict__ col_sorted) {
  int i = blockIdx.x * blockDim.x + threadIdx.x;
  int stride = gridDim.x * blockDim.x;
  for (; i < N_EDGES; i += stride) {
    int r = row[i];
    int pos = row_start[r] + atomicAdd(&fill[r], 1);
    col_sorted[pos] = col[i];
  }
}

// ---------------- W transpose to bf16: Wt[n][k] = bf16(W[k][n]) ----------------
__global__ void k_wt(const float* __restrict__ W, ushort* __restrict__ Wt, int K, int N) {
  int idx = blockIdx.x * 256 + threadIdx.x;
  if (idx >= K * N) return;
  int n = idx / K, k = idx % K;
  Wt[idx] = f2bf(W[(size_t)k * N + n]);
}

// ---------------- bf16 MFMA GEMM: hs = bf16( f(A) @ W * d_isqrt ) ----------------
// APPLY_BN: A is bf16 [N,256], f(A)=relu(A*scale+shift). else A fp32 [N,256], f=id.
// Wt: [D,256] bf16 (W transposed); hs: [N_NODES,D] bf16.
// BM=BN=128, BK=32, 256 threads = 4 waves (2x2), 64x64/wave, 4x4 mfma_16x16x32_bf16.
template <int D, bool APPLY_BN>
__global__ __launch_bounds__(256, 2) void k_gemm_bf16(const void* __restrict__ Av,
                                                      const ushort* __restrict__ Wt,
                                                      const float* __restrict__ ss,
                                                      const float* __restrict__ dis,
                                                      ushort* __restrict__ hs) {
  constexpr int BM = 128, BN = 128, BK = 32, K = 256;
  constexpr int LDP = BK + 8;  // 40 bf16 (80B) stride: conflict-free b128 frags
  __shared__ ushort As[BM * LDP];
  __shared__ ushort Bs[BN * LDP];
  const int tid = threadIdx.x;
  const int lane = tid & 63;
  const int wid = tid >> 6;
  const int wr = wid >> 1, wc = wid & 1;  // 2x2 wave grid
  constexpr int NB = D / BN;
  const int rb = (blockIdx.x / NB) * BM;
  const int cb = (blockIdx.x % NB) * BN;

  f32x4 acc[4][4];
#pragma unroll
  for (int m = 0; m < 4; ++m)
#pragma unroll
    for (int n = 0; n < 4; ++n) acc[m][n] = (f32x4)(0.f);

  for (int kt = 0; kt < K; kt += BK) {
    // stage A: 128 rows x 32 k. 512 tasks of 8 elems.
#pragma unroll
    for (int it = 0; it < 2; ++it) {
      int idx = tid + it * 256;
      int row = idx >> 2, kq = idx & 3;
      int gr = rb + row;
      if (gr >= N_NODES) gr = N_NODES - 1;
      float e[8];
      if constexpr (APPLY_BN) {
        const ushort* A = (const ushort*)Av;
        short8 v = *reinterpret_cast<const short8*>(&A[(size_t)gr * K + kt + kq * 8]);
#pragma unroll
        for (int q = 0; q < 8; ++q) {
          int k = kt + kq * 8 + q;
          e[q] = fmaxf(bf2f((ushort)v[q]) * ss[k] + ss[256 + k], 0.f);
        }
      } else {
        const float* A = (const float*)Av;
        const float4* src = reinterpret_cast<const float4*>(&A[(size_t)gr * K + kt + kq * 8]);
        float4 v0 = src[0], v1 = src[1];
        e[0] = v0.x; e[1] = v0.y; e[2] = v0.z; e[3] = v0.w;
        e[4] = v1.x; e[5] = v1.y; e[6] = v1.z; e[7] = v1.w;
      }
      short8 pk;
#pragma unroll
      for (int q = 0; q < 8; ++q) pk[q] = (short)f2bf(e[q]);
      *reinterpret_cast<short8*>(&As[row * LDP + kq * 8]) = pk;
    }
    // stage B from Wt (already bf16, k-contiguous)
#pragma unroll
    for (int it = 0; it < 2; ++it) {
      int idx = tid + it * 256;
      int n = idx >> 2, kq = idx & 3;
      short8 v = *reinterpret_cast<const short8*>(&Wt[(size_t)(cb + n) * K + kt + kq * 8]);
      *reinterpret_cast<short8*>(&Bs[n * LDP + kq * 8]) = v;
    }
    __syncthreads();

    const int rl = lane & 15;
    const int kb = (lane >> 4) * 8;
    short8 af[4], bfr[4];
#pragma unroll
    for (int f = 0; f < 4; ++f) {
      af[f] = *reinterpret_cast<short8*>(&As[(wr * 64 + f * 16 + rl) * LDP + kb]);
      bfr[f] = *reinterpret_cast<short8*>(&Bs[(wc * 64 + f * 16 + rl) * LDP + kb]);
    }
#pragma unroll
    for (int m = 0; m < 4; ++m)
#pragma unroll
      for (int n = 0; n < 4; ++n)
        acc[m][n] = __builtin_amdgcn_mfma_f32_16x16x32_bf16(af[m], bfr[n], acc[m][n], 0, 0, 0);
    __syncthreads();
  }

  // epilogue: *dis[row], cvt bf16, store. C frag: col=lane&15, row=(lane>>4)*4+j.
  const int cl = lane & 15;
  const int rq = lane >> 4;
#pragma unroll
  for (int m = 0; m < 4; ++m) {
    int rbase = rb + wr * 64 + m * 16 + rq * 4;
#pragma unroll
    for (int j = 0; j < 4; ++j) {
      int row = rbase + j;
      if (row >= N_NODES) continue;
      float di = dis[row];
#pragma unroll
      for (int n = 0; n < 4; ++n) {
        int col = cb + wc * 64 + n * 16 + cl;
        hs[(size_t)row * D + col] = f2bf(acc[m][n][j] * di);
      }
    }
  }
}

// ---------------- aggregation (bf16 gather): pre = bf16(dis*(self+sum_nbr)+b) -------
// wave per node, lane = 4 cols (D=256). Indices batch-loaded + __shfl broadcast;
// gather loop unrolled x8: eight independent 512B row-reads in flight.
__global__ __launch_bounds__(256) void k_agg_bf16(const ushort* __restrict__ hs,
                                                  const int* __restrict__ cs,
                                                  const int* __restrict__ rs,
                                                  const float* __restrict__ dis,
                                                  const float* __restrict__ bias,
                                                  ushort* __restrict__ pre) {
  int gw = (blockIdx.x * 256 + threadIdx.x) >> 6;
  if (gw >= N_NODES) return;
  int lane = threadIdx.x & 63;
  size_t coff = (size_t)lane * 4;
  ushort4 sv = *reinterpret_cast<const ushort4*>(&hs[(size_t)gw * 256 + coff]);
  float a0 = bf2f(sv.x), a1 = bf2f(sv.y), a2 = bf2f(sv.z), a3 = bf2f(sv.w);
  int s = rs[gw], e = rs[gw + 1];
  for (int base = s; base < e; base += 64) {
    int nav = min(64, e - base);
    int idx = (base + lane < e) ? cs[base + lane] : 0;
    int j = 0;
    for (; j + 7 < nav; j += 8) {
      ushort4 v[8];
#pragma unroll
      for (int u = 0; u < 8; ++u) {
        int c = __shfl(idx, j + u);
        v[u] = *reinterpret_cast<const ushort4*>(&hs[(size_t)c * 256 + coff]);
      }
#pragma unroll
      for (int u = 0; u < 8; ++u) {
        a0 += bf2f(v[u].x);
        a1 += bf2f(v[u].y);
        a2 += bf2f(v[u].z);
        a3 += bf2f(v[u].w);
      }
    }
    for (; j < nav; ++j) {
      int c0 = __shfl(idx, j);
      ushort4 v0 = *reinterpret_cast<const ushort4*>(&hs[(size_t)c0 * 256 + coff]);
      a0 += bf2f(v0.x);
      a1 += bf2f(v0.y);
      a2 += bf2f(v0.z);
      a3 += bf2f(v0.w);
    }
  }
  float di = dis[gw];
  float4 b = *reinterpret_cast<const float4*>(&bias[lane * 4]);
  ushort4 o;
  o.x = f2bf(a0 * di + b.x);
  o.y = f2bf(a1 * di + b.y);
  o.z = f2bf(a2 * di + b.z);
  o.w = f2bf(a3 * di + b.w);
  *reinterpret_cast<ushort4*>(&pre[(size_t)gw * 256 + coff]) = o;
}

// layer-3 aggregation fused with log_softmax, D=128, wave per node (lane: 2 cols)
__global__ __launch_bounds__(256) void k_agg_lsm_bf16(const ushort* __restrict__ hs,
                                                      const int* __restrict__ cs,
                                                      const int* __restrict__ rs,
                                                      const float* __restrict__ dis,
                                                      const float* __restrict__ bias,
                                                      float* __restrict__ out) {
  int gw = (blockIdx.x * 256 + threadIdx.x) >> 6;
  if (gw >= N_NODES) return;
  int lane = threadIdx.x & 63;
  ushort2 sv = *reinterpret_cast<const ushort2*>(&hs[(size_t)gw * 128 + lane * 2]);
  float a0 = bf2f(sv.x), a1 = bf2f(sv.y);
  int s = rs[gw], e = rs[gw + 1];
  for (int base = s; base < e; base += 64) {
    int nav = min(64, e - base);
    int idx = (base + lane < e) ? cs[base + lane] : 0;
    int j = 0;
    for (; j + 7 < nav; j += 8) {
      ushort2 v[8];
#pragma unroll
      for (int u = 0; u < 8; ++u) {
        int c = __shfl(idx, j + u);
        v[u] = *reinterpret_cast<const ushort2*>(&hs[(size_t)c * 128 + lane * 2]);
      }
#pragma unroll
      for (int u = 0; u < 8; ++u) {
        a0 += bf2f(v[u].x);
        a1 += bf2f(v[u].y);
      }
    }
    for (; j < nav; ++j) {
      int c0 = __shfl(idx, j);
      ushort2 v0 = *reinterpret_cast<const ushort2*>(&hs[(size_t)c0 * 128 + lane * 2]);
      a0 += bf2f(v0.x);
      a1 += bf2f(v0.y);
    }
  }
  float di = dis[gw];
  float2 b = *reinterpret_cast<const float2*>(&bias[lane * 2]);
  float v0 = a0 * di + b.x, v1 = a1 * di + b.y;
  float m = fmaxf(v0, v1);
#pragma unroll
  for (int o = 1; o < 64; o <<= 1) m = fmaxf(m, __shfl_xor(m, o));
  float sum = __expf(v0 - m) + __expf(v1 - m);
#pragma unroll
  for (int o = 1; o < 64; o <<= 1) sum += __shfl_xor(sum, o);
  float ls = m + logf(sum);
  float2 o2 = {v0 - ls, v1 - ls};
  *reinterpret_cast<float2*>(&out[(size_t)gw * 128 + lane * 2]) = o2;
}

// ---------------- batchnorm stats: three-phase, atomic-free ----------------
// Phase A: block handles 2 rows/iter (coalesced 1KB), regs accumulate per-col,
// LDS combine, write partial[block][512] (sum[256] | sq[256]).
__global__ __launch_bounds__(256) void k_bnstatsA(const ushort* __restrict__ pre,
                                                  float* __restrict__ partial) {
  int t = threadIdx.x;
  int rsub = t >> 7;         // 0/1: which row of the pair
  int cp = (t & 127) * 2;    // column pair
  float s0 = 0.f, s1 = 0.f, q0 = 0.f, q1 = 0.f;
  for (int r = blockIdx.x * 2 + rsub; r < N_NODES; r += BNA_BLOCKS * 2) {
    ushort2 v = *reinterpret_cast<const ushort2*>(&pre[(size_t)r * 256 + cp]);
    float f0 = bf2f(v.x), f1 = bf2f(v.y);
    s0 += f0;
    q0 += f0 * f0;
    s1 += f1;
    q1 += f1 * f1;
  }
  __shared__ float lsum[256], lsq[256];
  if (rsub) {
    lsum[cp] = s0;
    lsum[cp + 1] = s1;
    lsq[cp] = q0;
    lsq[cp + 1] = q1;
  }
  __syncthreads();
  if (!rsub) {
    float* p = &partial[(size_t)blockIdx.x * 512];
    p[cp] = s0 + lsum[cp];
    p[cp + 1] = s1 + lsum[cp + 1];
    p[256 + cp] = q0 + lsq[cp];
    p[256 + cp + 1] = q1 + lsq[cp + 1];
  }
}

// Phase B: 8 blocks x 512 threads; block b reduces partial rows [b*32, b*32+32).
__global__ __launch_bounds__(512) void k_bnstatsB(const float* __restrict__ partial,
                                                  float* __restrict__ p2) {
  int t = threadIdx.x, b = blockIdx.x;
  float a = 0.f;
#pragma unroll 8
  for (int r = 0; r < BNA_BLOCKS / 8; ++r)
    a += partial[(size_t)(b * (BNA_BLOCKS / 8) + r) * 512 + t];
  p2[(size_t)b * 512 + t] = a;
}

// Phase C: fold 8-way sum + compute scale/shift.
__global__ void k_bnfinal(const float* __restrict__ p2, const float* __restrict__ gamma,
                          const float* __restrict__ beta, float* __restrict__ ss) {
  int t = threadIdx.x;
  float sum = 0.f, sq = 0.f;
#pragma unroll
  for (int b = 0; b < 8; ++b) {
    sum += p2[(size_t)b * 512 + t];
    sq += p2[(size_t)b * 512 + 256 + t];
  }
  float mu = sum * (1.f / N_NODES);
  float var = sq * (1.f / N_NODES) - mu * mu;
  float sc = gamma[t] * rsqrtf(var + BN_EPS);
  ss[t] = sc;
  ss[256 + t] = beta[t] - mu * sc;
}

// ---------------- launcher ----------------
extern "C" void kernel_launch(void* const* d_in, const int* in_sizes, int n_in,
                              void* d_out, int out_size, void* d_ws, size_t ws_size,
                              hipStream_t stream) {
  const float* x = (const float*)d_in[0];
  const int* erow = (const int*)d_in[1];
  const int* ecol = erow + N_EDGES;
  const float* W0 = (const float*)d_in[2];
  const float* b0 = (const float*)d_in[3];
  const float* W1 = (const float*)d_in[4];
  const float* b1 = (const float*)d_in[5];
  const float* W2 = (const float*)d_in[6];
  const float* b2 = (const float*)d_in[7];
  const float* g0 = (const float*)d_in[8];
  const float* be0 = (const float*)d_in[9];
  const float* g1 = (const float*)d_in[10];
  const float* be1 = (const float*)d_in[11];
  float* out = (float*)d_out;

  char* ws = (char*)d_ws;
  size_t off = 0;
  auto take = [&](size_t bytes) {
    char* p = ws + off;
    off = (off + bytes + 255) & ~(size_t)255;
    return p;
  };
  int* deg = (int*)take(N_NODES * 4);
  int* fill = (int*)take(N_NODES * 4);
  size_t zero_bytes = off;  // deg+fill must start at 0 each call
  float* bnpart = (float*)take((size_t)BNA_BLOCKS * 512 * 4);
  float* bnpart2 = (float*)take(8 * 512 * 4);
  float* dis = (float*)take(N_NODES * 4);
  int* row_start = (int*)take((N_NODES + 1) * 4);
  int* bsum = (int*)take(256 * 4);
  int* boff = (int*)take(256 * 4);
  float* ss0 = (float*)take(512 * 4);
  float* ss1 = (float*)take(512 * 4);
  ushort* Wt0 = (ushort*)take(256 * 256 * 2);
  ushort* Wt1 = (ushort*)take(256 * 256 * 2);
  ushort* Wt2 = (ushort*)take(256 * 128 * 2);
  int* col_sorted = (int*)take((size_t)N_EDGES * 4);
  ushort* hs = (ushort*)take((size_t)N_NODES * 256 * 2);
  ushort* pre = (ushort*)take((size_t)N_NODES * 256 * 2);
  if (off > ws_size) return;

  hipMemsetAsync(d_ws, 0, zero_bytes, stream);

  k_deg<<<1024, 256, 0, stream>>>(erow, deg);
  k_disqrt<<<(N_NODES + 255) / 256, 256, 0, stream>>>(deg, dis);
  int nb = (N_NODES + 255) / 256;  // 196
  k_scan_part<<<nb, 256, 0, stream>>>(deg, bsum);
  k_scan_top<<<1, 256, 0, stream>>>(bsum, boff, nb);
  k_scan_final<<<nb, 256, 0, stream>>>(deg, boff, row_start);
  k_scatter<<<1024, 256, 0, stream>>>(erow, ecol, row_start, fill, col_sorted);

  k_wt<<<(256 * 256 + 255) / 256, 256, 0, stream>>>(W0, Wt0, 256, 256);
  k_wt<<<(256 * 256 + 255) / 256, 256, 0, stream>>>(W1, Wt1, 256, 256);
  k_wt<<<(256 * 128 + 255) / 256, 256, 0, stream>>>(W2, Wt2, 256, 128);

  int mblocks = (N_NODES + 127) / 128;  // 391
  int agg_grid = (N_NODES * 64 + 255) / 256;  // 12500
  // layer 0
  k_gemm_bf16<256, false><<<mblocks * 2, 256, 0, stream>>>(x, Wt0, nullptr, dis, hs);
  k_agg_bf16<<<agg_grid, 256, 0, stream>>>(hs, col_sorted, row_start, dis, b0, pre);
  k_bnstatsA<<<BNA_BLOCKS, 256, 0, stream>>>(pre, bnpart);
  k_bnstatsB<<<8, 512, 0, stream>>>(bnpart, bnpart2);
  k_bnfinal<<<1, 256, 0, stream>>>(bnpart2, g0, be0, ss0);
  // layer 1
  k_gemm_bf16<256, true><<<mblocks * 2, 256, 0, stream>>>(pre, Wt1, ss0, dis, hs);
  k_agg_bf16<<<agg_grid, 256, 0, stream>>>(hs, col_sorted, row_start, dis, b1, pre);
  k_bnstatsA<<<BNA_BLOCKS, 256, 0, stream>>>(pre, bnpart);
  k_bnstatsB<<<8, 512, 0, stream>>>(bnpart, bnpart2);
  k_bnfinal<<<1, 256, 0, stream>>>(bnpart2, g1, be1, ss1);
  // layer 2 + log_softmax
  k_gemm_bf16<128, true><<<mblocks, 256, 0, stream>>>(pre, Wt2, ss1, dis, hs);
  k_agg_lsm_bf16<<<agg_grid, 256, 0, stream>>>(hs, col_sorted, row_start, dis, b2, out);
}